// Round 16
// baseline (131.544 us; speedup 1.0000x reference)
//
#include <hip/hip_runtime.h>
#include <hip/hip_fp16.h>

#define N_NODES   100000
#define N_EDGES   1600000
#define N_FEAT    100
#define HIDDEN    64
#define N_CLASSES 47
#define ZPAD      48
#define NBIN      ((N_NODES + 255) / 256)   // 391 radix bins (dest >> 8)
#define SBLK      512                        // scatter blocks
#define CHUNK     (N_EDGES / SBLK)           // 3125 edges per scatter block
#define NHIST     (NBIN * SBLK)              // 200192 histogram entries
#define WT0_ELEMS (HIDDEN * 128)             // 8192
#define WT1_ELEMS (ZPAD * 64)                // 3072
#define WPREP_N   (WT0_ELEMS + WT1_ELEMS)    // 11264

typedef _Float16 f16x8 __attribute__((ext_vector_type(8)));
typedef float f32x4 __attribute__((ext_vector_type(4)));

// ---------------- scan: 512-thread blocks, one block per bin ----------------

__global__ __launch_bounds__(512) void k_gscan1(const int* __restrict__ in,
                                                int* __restrict__ out,
                                                int* __restrict__ sums, int n) {
    __shared__ int tmp[512];
    int i = blockIdx.x * 512 + threadIdx.x;
    int v = (i < n) ? in[i] : 0;
    tmp[threadIdx.x] = v;
    __syncthreads();
    for (int off = 1; off < 512; off <<= 1) {
        int t = (threadIdx.x >= off) ? tmp[threadIdx.x - off] : 0;
        __syncthreads();
        tmp[threadIdx.x] += t;
        __syncthreads();
    }
    if (i < n) out[i] = tmp[threadIdx.x] - v;   // bin-local exclusive
    if (threadIdx.x == 511) sums[blockIdx.x] = tmp[511];
}

__global__ __launch_bounds__(512) void k_gscan2(int* __restrict__ sums, int nb) {
    __shared__ int tmp[512];
    int i = threadIdx.x;
    int v = (i < nb) ? sums[i] : 0;
    tmp[i] = v;
    __syncthreads();
    for (int off = 1; off < 512; off <<= 1) {
        int t = (i >= off) ? tmp[i - off] : 0;
        __syncthreads();
        tmp[i] += t;
        __syncthreads();
    }
    if (i < nb) sums[i] = tmp[i] - v;   // exclusive
}

// ---------------- radix pass: bin = dest >> 8 (256 nodes/bin) ----------------

// fused: blocks 0..43 also do the weight transpose (wprep)
__global__ __launch_bounds__(256) void k_hist(const int* __restrict__ ecol,
                                              int* __restrict__ gh,
                                              const float* __restrict__ W0,
                                              const float* __restrict__ W1,
                                              __half* __restrict__ wt0,
                                              __half* __restrict__ wt1) {
    int wi = blockIdx.x * 256 + threadIdx.x;
    if (wi < WT0_ELEMS) {
        int n = wi >> 7, k = wi & 127;
        wt0[wi] = __float2half((k < N_FEAT) ? W0[k * HIDDEN + n] : 0.0f);
    } else if (wi < WPREP_N) {
        int j = wi - WT0_ELEMS;
        int n = j >> 6, k = j & 63;
        wt1[j] = __float2half((n < N_CLASSES) ? W1[k * N_CLASSES + n] : 0.0f);
    }

    __shared__ int lh[NBIN];
    int b = blockIdx.x, t = threadIdx.x;
    for (int i = t; i < NBIN; i += 256) lh[i] = 0;
    __syncthreads();
    int e0 = b * CHUNK;
    for (int i = t; i < CHUNK; i += 256)
        atomicAdd(&lh[ecol[e0 + i] >> 8], 1);
    __syncthreads();
    for (int i = t; i < NBIN; i += 256) gh[i * SBLK + b] = lh[i];
}

// payload: row (17 bits) | (dest & 255) << 17
__global__ __launch_bounds__(256) void k_radix_scatter(
    const int* __restrict__ erow, const int* __restrict__ ecol,
    const int* __restrict__ gpos, const int* __restrict__ hsums,
    int* __restrict__ pairs) {
    __shared__ int lc[NBIN];
    int b = blockIdx.x, t = threadIdx.x;
    for (int i = t; i < NBIN; i += 256) lc[i] = gpos[i * SBLK + b] + hsums[i];
    __syncthreads();
    int e0 = b * CHUNK;
    for (int i = t; i < CHUNK; i += 256) {
        int e = e0 + i;
        int r = erow[e], c = ecol[e];
        int pos = atomicAdd(&lc[c >> 8], 1);
        pairs[pos] = r | ((c & 255) << 17);
    }
}

// one block per bin, 1024 threads: degree count -> LDS scan -> rp/dinv -> place
__global__ __launch_bounds__(1024) void k_binfinish(
    const int* __restrict__ gpos, const int* __restrict__ hsums,
    const int* __restrict__ pairs,
    int* __restrict__ rp, float* __restrict__ dinv, int* __restrict__ eidx) {
    __shared__ int cnt[256];
    __shared__ int tmp[256];
    int b = blockIdx.x, t = threadIdx.x;
    int n0 = b << 8;
    int beg = gpos[b * SBLK] + hsums[b];
    int end = (b + 1 < NBIN) ? gpos[(b + 1) * SBLK] + hsums[b + 1] : N_EDGES;

    if (t < 256) cnt[t] = 0;
    __syncthreads();
    for (int i = beg + t; i < end; i += 1024)
        atomicAdd(&cnt[(pairs[i] >> 17) & 255], 1);
    __syncthreads();
    int v = 0;
    if (t < 256) { v = cnt[t]; tmp[t] = v; }
    __syncthreads();
    for (int off = 1; off < 256; off <<= 1) {
        int u = (t < 256 && t >= off) ? tmp[t - off] : 0;
        __syncthreads();
        if (t < 256) tmp[t] += u;
        __syncthreads();
    }
    if (t < 256) {
        int rpv = beg + tmp[t] - v;
        int n = n0 + t;
        if (n < N_NODES) {
            rp[n] = rpv;
            dinv[n] = rsqrtf(1.0f + (float)v);
        }
        cnt[t] = rpv;   // placement cursor
    }
    if (b == NBIN - 1 && t == 0) rp[N_NODES] = N_EDGES;
    __syncthreads();
    for (int i = beg + t; i < end; i += 1024) {
        int p = pairs[i];
        int pos = atomicAdd(&cnt[(p >> 17) & 255], 1);
        eidx[pos] = p & 0x1FFFF;
    }
}

// -------- layer 0 GEMM (MFMA): yh = fp16( dinv[row] * (x @ W0) )
// Rows N_NODES..100031 (grid padding) are written as ZEROS.
__global__ __launch_bounds__(256) void k_gemm1(
    const float* __restrict__ x, const __half* __restrict__ wt0,
    const float* __restrict__ dinv, __half* __restrict__ yh) {
    int w = threadIdx.x >> 6, l = threadIdx.x & 63;
    int g = l >> 4, c16 = l & 15;
    int row = blockIdx.x * 64 + w * 16 + c16;
    int rl = (row < N_NODES) ? row : (N_NODES - 1);
    const float* xr = x + (size_t)rl * N_FEAT;

    f16x8 a[4];
    #pragma unroll
    for (int s = 0; s < 4; ++s) {
        int k0 = 32 * s + 8 * g;
        float4 f0 = (k0 + 3 < N_FEAT) ? *(const float4*)(xr + k0)
                                      : make_float4(0.f, 0.f, 0.f, 0.f);
        float4 f1 = (k0 + 7 < N_FEAT) ? *(const float4*)(xr + k0 + 4)
                                      : make_float4(0.f, 0.f, 0.f, 0.f);
        a[s][0] = (_Float16)f0.x; a[s][1] = (_Float16)f0.y;
        a[s][2] = (_Float16)f0.z; a[s][3] = (_Float16)f0.w;
        a[s][4] = (_Float16)f1.x; a[s][5] = (_Float16)f1.y;
        a[s][6] = (_Float16)f1.z; a[s][7] = (_Float16)f1.w;
    }
    f32x4 acc0 = {0,0,0,0}, acc1 = {0,0,0,0}, acc2 = {0,0,0,0}, acc3 = {0,0,0,0};
    #pragma unroll
    for (int s = 0; s < 4; ++s) {
        int ko = 32 * s + 8 * g;
        f16x8 b0 = *(const f16x8*)(wt0 + (0 * 16 + c16) * 128 + ko);
        f16x8 b1 = *(const f16x8*)(wt0 + (1 * 16 + c16) * 128 + ko);
        f16x8 b2 = *(const f16x8*)(wt0 + (2 * 16 + c16) * 128 + ko);
        f16x8 b3 = *(const f16x8*)(wt0 + (3 * 16 + c16) * 128 + ko);
        acc0 = __builtin_amdgcn_mfma_f32_16x16x32_f16(a[s], b0, acc0, 0, 0, 0);
        acc1 = __builtin_amdgcn_mfma_f32_16x16x32_f16(a[s], b1, acc1, 0, 0, 0);
        acc2 = __builtin_amdgcn_mfma_f32_16x16x32_f16(a[s], b2, acc2, 0, 0, 0);
        acc3 = __builtin_amdgcn_mfma_f32_16x16x32_f16(a[s], b3, acc3, 0, 0, 0);
    }
    int orow = blockIdx.x * 64 + w * 16 + 4 * g;
    #pragma unroll
    for (int r = 0; r < 4; ++r) {
        int rr = orow + r;                      // grid max = 100031
        float di = (rr < N_NODES) ? dinv[rr] : 0.0f;
        size_t base = (size_t)rr * HIDDEN + c16;
        yh[base +  0] = __float2half(di * acc0[r]);
        yh[base + 16] = __float2half(di * acc1[r]);
        yh[base + 32] = __float2half(di * acc2[r]);
        yh[base + 48] = __float2half(di * acc3[r]);
    }
}

// -------- fused layer-0 aggregate + layer-1 GEMM --------------------------
// Gather batches: load half2s, mask invalid slots to zero with ONE cndmask on
// the packed reg, reduce 16->1 via v_pk_add_f16 tree (depth 4), add batch sum
// to f32 acc. Per-slot VALU: ~2 ops vs 7 in R13 (the R13 VALU bottleneck).
__global__ __launch_bounds__(256) void k_agg0(
    const int* __restrict__ rp, const int* __restrict__ eidx,
    const float* __restrict__ dinv, const __half* __restrict__ yh,
    const float* __restrict__ b0, const __half* __restrict__ wt1,
    __half* __restrict__ zh) {
    __shared__ __half hs[16][64];   // rows 0-7 = this block's hr; 8-15 zero
    int t = blockIdx.x * 256 + threadIdx.x;
    int n = t >> 5;                 // grid exactly 12500 blocks: n < N_NODES
    int hl = threadIdx.x & 31;
    int nl = threadIdx.x >> 5;

    ((__half2*)hs)[256 + threadIdx.x] = __floats2half2_rn(0.f, 0.f); // rows 8-15

    int beg = rp[n], end = rp[n + 1];
    int deg = end - beg;
    int se = (beg + hl < end) ? eidx[beg + hl] : 0;
    const __half2* yh2 = (const __half2*)yh;
    float2 fs = __half22float2(yh2[(size_t)n * 32 + hl]);   // self loop
    float ax = fs.x, ay = fs.y;
    int m = deg < 32 ? deg : 32;
    int base = threadIdx.x & 32;
    const __half2 hz = __floats2half2_rn(0.f, 0.f);

    {   // batch 0: slots 0..15
        __half2 h[16];
        #pragma unroll
        for (int k = 0; k < 16; ++k) {
            int s = __shfl(se, base + k);
            h[k] = yh2[(size_t)s * 32 + hl];
        }
        #pragma unroll
        for (int k = 0; k < 16; ++k) h[k] = (m > k) ? h[k] : hz;
        #pragma unroll
        for (int s2 = 8; s2 >= 1; s2 >>= 1) {
            #pragma unroll
            for (int k = 0; k < s2; ++k) h[k] = __hadd2(h[2 * k], h[2 * k + 1]);
        }
        float2 bs = __half22float2(h[0]);
        ax += bs.x; ay += bs.y;
    }
    if (m > 16) {   // batch 1: slots 16..31
        __half2 h[16];
        #pragma unroll
        for (int k = 0; k < 16; ++k) {
            int s = __shfl(se, base + 16 + k);
            h[k] = yh2[(size_t)s * 32 + hl];
        }
        #pragma unroll
        for (int k = 0; k < 16; ++k) h[k] = (m > 16 + k) ? h[k] : hz;
        #pragma unroll
        for (int s2 = 8; s2 >= 1; s2 >>= 1) {
            #pragma unroll
            for (int k = 0; k < s2; ++k) h[k] = __hadd2(h[2 * k], h[2 * k + 1]);
        }
        float2 bs = __half22float2(h[0]);
        ax += bs.x; ay += bs.y;
    }
    if (deg > 32) {
        for (int e = beg + 32; e < end; ++e) {
            int s = eidx[e];
            float2 fv = __half22float2(yh2[(size_t)s * 32 + hl]);
            ax += fv.x; ay += fv.y;
        }
    }
    float di = dinv[n];
    float2 b2 = ((const float2*)b0)[hl];
    float o0 = fmaxf(di * ax + b2.x, 0.0f);
    float o1 = fmaxf(di * ay + b2.y, 0.0f);
    ((__half2*)hs)[nl * 32 + hl] = __floats2half2_rn(o0, o1);
    __syncthreads();

    // ---- epilogue: wave 0 computes zh rows for the block's 8 nodes -------
    if (threadIdx.x < 64) {
        int l = threadIdx.x;
        int g = l >> 4, c16 = l & 15;
        f16x8 a0 = *(const f16x8*)(&hs[c16][8 * g]);
        f16x8 a1 = *(const f16x8*)(&hs[c16][32 + 8 * g]);
        f32x4 acc0 = {0,0,0,0}, acc1 = {0,0,0,0}, acc2 = {0,0,0,0};
        #pragma unroll
        for (int s = 0; s < 2; ++s) {
            int ko = 32 * s + 8 * g;
            f16x8 b0f = *(const f16x8*)(wt1 + (0 * 16 + c16) * 64 + ko);
            f16x8 b1f = *(const f16x8*)(wt1 + (1 * 16 + c16) * 64 + ko);
            f16x8 b2f = *(const f16x8*)(wt1 + (2 * 16 + c16) * 64 + ko);
            f16x8 av = s ? a1 : a0;
            acc0 = __builtin_amdgcn_mfma_f32_16x16x32_f16(av, b0f, acc0, 0, 0, 0);
            acc1 = __builtin_amdgcn_mfma_f32_16x16x32_f16(av, b1f, acc1, 0, 0, 0);
            acc2 = __builtin_amdgcn_mfma_f32_16x16x32_f16(av, b2f, acc2, 0, 0, 0);
        }
        if (g < 2) {   // D rows 0..7 are the valid ones
            int nrow = blockIdx.x * 8 + 4 * g;
            #pragma unroll
            for (int r = 0; r < 4; ++r) {
                float dr = dinv[nrow + r];
                size_t bz = (size_t)(nrow + r) * ZPAD + c16;
                zh[bz +  0] = __float2half(dr * acc0[r]);
                zh[bz + 16] = __float2half(dr * acc1[r]);
                zh[bz + 32] = __float2half(dr * acc2[r]);
            }
        }
    }
}

// -------- layer 1 aggregate: out[n] = dinv[n]*(zh[n]+sum zh[src]) + b1 ------
// Loads guarded by hl<24 (R14's hoist was the regression); fp16 tree reduce.
__global__ __launch_bounds__(256) void k_agg1(
    const int* __restrict__ rp, const int* __restrict__ eidx,
    const float* __restrict__ dinv, const __half* __restrict__ zh,
    const float* __restrict__ b1, float* __restrict__ out) {
    int t = blockIdx.x * 256 + threadIdx.x;
    int n = t >> 5;
    int hl = threadIdx.x & 31;
    if (n >= N_NODES) return;
    int beg = rp[n], end = rp[n + 1];
    int deg = end - beg;
    int se = (beg + hl < end) ? eidx[beg + hl] : 0;
    const __half2* zh2 = (const __half2*)zh;
    float ax = 0.0f, ay = 0.0f;
    if (hl < 24) {
        float2 f = __half22float2(zh2[(size_t)n * 24 + hl]);
        ax = f.x; ay = f.y;
    }
    int m = deg < 32 ? deg : 32;
    int base = threadIdx.x & 32;
    const __half2 hz = __floats2half2_rn(0.f, 0.f);

    {   // batch 0: slots 0..15
        int sidx[16];
        #pragma unroll
        for (int k = 0; k < 16; ++k) sidx[k] = __shfl(se, base + k);
        if (hl < 24) {
            __half2 h[16];
            #pragma unroll
            for (int k = 0; k < 16; ++k) h[k] = zh2[(size_t)sidx[k] * 24 + hl];
            #pragma unroll
            for (int k = 0; k < 16; ++k) h[k] = (m > k) ? h[k] : hz;
            #pragma unroll
            for (int s2 = 8; s2 >= 1; s2 >>= 1) {
                #pragma unroll
                for (int k = 0; k < s2; ++k) h[k] = __hadd2(h[2 * k], h[2 * k + 1]);
            }
            float2 bs = __half22float2(h[0]);
            ax += bs.x; ay += bs.y;
        }
    }
    if (m > 16) {   // batch 1: slots 16..31
        int sidx[16];
        #pragma unroll
        for (int k = 0; k < 16; ++k) sidx[k] = __shfl(se, base + 16 + k);
        if (hl < 24) {
            __half2 h[16];
            #pragma unroll
            for (int k = 0; k < 16; ++k) h[k] = zh2[(size_t)sidx[k] * 24 + hl];
            #pragma unroll
            for (int k = 0; k < 16; ++k) h[k] = (m > 16 + k) ? h[k] : hz;
            #pragma unroll
            for (int s2 = 8; s2 >= 1; s2 >>= 1) {
                #pragma unroll
                for (int k = 0; k < s2; ++k) h[k] = __hadd2(h[2 * k], h[2 * k + 1]);
            }
            float2 bs = __half22float2(h[0]);
            ax += bs.x; ay += bs.y;
        }
    }
    if (deg > 32) {
        for (int e = beg + 32; e < end; ++e) {
            int s = eidx[e];
            if (hl < 24) {
                float2 fv = __half22float2(zh2[(size_t)s * 24 + hl]);
                ax += fv.x; ay += fv.y;
            }
        }
    }
    if (hl < 24) {
        float di = dinv[n];
        out[(size_t)n * N_CLASSES + 2 * hl] = di * ax + b1[2 * hl];
        if (hl < 23)
            out[(size_t)n * N_CLASSES + 2 * hl + 1] = di * ay + b1[2 * hl + 1];
    }
}

extern "C" void kernel_launch(void* const* d_in, const int* in_sizes, int n_in,
                              void* d_out, int out_size, void* d_ws, size_t ws_size,
                              hipStream_t stream) {
    const float* x  = (const float*)d_in[0];
    const int*   ei = (const int*)d_in[1];
    const float* W0 = (const float*)d_in[2];
    const float* b0 = (const float*)d_in[3];
    const float* W1 = (const float*)d_in[4];
    const float* b1 = (const float*)d_in[5];
    float* out = (float*)d_out;

    char* ws = (char*)d_ws;
    float*  dinv  = (float*)(ws);                         // 400 KB
    int*    rp    = (int*)(ws + 412 * 1024);              // 400 KB + 4
    int*    hsums = (int*)(ws + 824 * 1024);              // 1.6 KB (391 ints)
    int*    gh    = (int*)(ws + 828 * 1024);              // 782 KB
    int*    gpos  = (int*)(ws + 1612 * 1024);             // 782 KB
    __half* wt0   = (__half*)(ws + 2400 * 1024);          // 16 KB
    __half* wt1   = (__half*)(ws + 2420 * 1024);          // 6 KB
    int*    eidx  = (int*)(ws + 2428 * 1024);             // 6.4 MB -> ~8.8 MB
    __half* yh    = (__half*)(ws + 10ull * 1024 * 1024);  // 100032 rows = 12.81 MB
    __half* zh    = (__half*)(ws + 23ull * 1024 * 1024);  // 9.6 MB (own buffer)
    int*    pairs = (int*)zh;   // 6.4 MB alias: dead before k_agg0 writes zh

    const int* erow = ei;             // edge_index[0] (sources)
    const int* ecol = ei + N_EDGES;   // edge_index[1] (destinations)

    // radix pass (wprep fused into hist)
    k_hist  <<<SBLK, 256, 0, stream>>>(ecol, gh, W0, W1, wt0, wt1);
    k_gscan1<<<NBIN, 512, 0, stream>>>(gh, gpos, hsums, NHIST);
    k_gscan2<<<1, 512, 0, stream>>>(hsums, NBIN);
    k_radix_scatter<<<SBLK, 256, 0, stream>>>(erow, ecol, gpos, hsums, pairs);
    k_binfinish<<<NBIN, 1024, 0, stream>>>(gpos, hsums, pairs, rp, dinv, eidx);

    // layer 0 GEMM, then fused (layer-0 aggregate + layer-1 GEMM)
    k_gemm1<<<(N_NODES + 63) / 64, 256, 0, stream>>>(x, wt0, dinv, yh);
    k_agg0 <<<(N_NODES * 32) / 256, 256, 0, stream>>>(rp, eidx, dinv, yh, b0, wt1, zh);

    // layer 1 aggregate
    k_agg1 <<<(N_NODES * 32) / 256, 256, 0, stream>>>(rp, eidx, dinv, zh, b1, out);
}

// Round 17
// 127.548 us; speedup vs baseline: 1.0313x; 1.0313x over previous
//
#include <hip/hip_runtime.h>
#include <hip/hip_fp16.h>

#define N_NODES   100000
#define N_EDGES   1600000
#define N_FEAT    100
#define HIDDEN    64
#define N_CLASSES 47
#define ZROWH     64                         // zh row stride in halves (128 B line)
#define NBIN      ((N_NODES + 255) / 256)   // 391 radix bins (dest >> 8)
#define SBLK      512                        // scatter blocks
#define CHUNK     (N_EDGES / SBLK)           // 3125 edges per scatter block
#define NHIST     (NBIN * SBLK)              // 200192 histogram entries
#define WT0_ELEMS (HIDDEN * 128)             // 8192
#define WT1_ELEMS (48 * 64)                  // 3072
#define WPREP_N   (WT0_ELEMS + WT1_ELEMS)    // 11264

typedef _Float16 f16x8 __attribute__((ext_vector_type(8)));
typedef float f32x4 __attribute__((ext_vector_type(4)));

// ---------------- scan: 512-thread blocks, one block per bin ----------------

__global__ __launch_bounds__(512) void k_gscan1(const int* __restrict__ in,
                                                int* __restrict__ out,
                                                int* __restrict__ sums, int n) {
    __shared__ int tmp[512];
    int i = blockIdx.x * 512 + threadIdx.x;
    int v = (i < n) ? in[i] : 0;
    tmp[threadIdx.x] = v;
    __syncthreads();
    for (int off = 1; off < 512; off <<= 1) {
        int t = (threadIdx.x >= off) ? tmp[threadIdx.x - off] : 0;
        __syncthreads();
        tmp[threadIdx.x] += t;
        __syncthreads();
    }
    if (i < n) out[i] = tmp[threadIdx.x] - v;   // bin-local exclusive
    if (threadIdx.x == 511) sums[blockIdx.x] = tmp[511];   // bin total
}

// ---------------- radix pass: bin = dest >> 8 (256 nodes/bin) ----------------

// fused: blocks 0..43 also do the weight transpose (wprep)
__global__ __launch_bounds__(256) void k_hist(const int* __restrict__ ecol,
                                              int* __restrict__ gh,
                                              const float* __restrict__ W0,
                                              const float* __restrict__ W1,
                                              __half* __restrict__ wt0,
                                              __half* __restrict__ wt1) {
    int wi = blockIdx.x * 256 + threadIdx.x;
    if (wi < WT0_ELEMS) {
        int n = wi >> 7, k = wi & 127;
        wt0[wi] = __float2half((k < N_FEAT) ? W0[k * HIDDEN + n] : 0.0f);
    } else if (wi < WPREP_N) {
        int j = wi - WT0_ELEMS;
        int n = j >> 6, k = j & 63;
        wt1[j] = __float2half((n < N_CLASSES) ? W1[k * N_CLASSES + n] : 0.0f);
    }

    __shared__ int lh[NBIN];
    int b = blockIdx.x, t = threadIdx.x;
    for (int i = t; i < NBIN; i += 256) lh[i] = 0;
    __syncthreads();
    int e0 = b * CHUNK;
    for (int i = t; i < CHUNK; i += 256)
        atomicAdd(&lh[ecol[e0 + i] >> 8], 1);
    __syncthreads();
    for (int i = t; i < NBIN; i += 256) gh[i * SBLK + b] = lh[i];
}

// 512 threads; inline exclusive scan of the 391 bin totals (replaces gscan2).
// payload: row (17 bits) | (dest & 255) << 17
__global__ __launch_bounds__(512) void k_radix_scatter(
    const int* __restrict__ erow, const int* __restrict__ ecol,
    const int* __restrict__ gpos, const int* __restrict__ bsums,
    int* __restrict__ pairs) {
    __shared__ int lc[NBIN];
    __shared__ int sc[512];
    int b = blockIdx.x, t = threadIdx.x;
    int bv = (t < NBIN) ? bsums[t] : 0;
    sc[t] = bv;
    __syncthreads();
    for (int off = 1; off < 512; off <<= 1) {
        int u = (t >= off) ? sc[t - off] : 0;
        __syncthreads();
        sc[t] += u;
        __syncthreads();
    }
    if (t < NBIN) lc[t] = gpos[t * SBLK + b] + sc[t] - bv;   // + excl prefix
    __syncthreads();
    int e0 = b * CHUNK;
    for (int i = t; i < CHUNK; i += 512) {
        int e = e0 + i;
        int r = erow[e], c = ecol[e];
        int pos = atomicAdd(&lc[c >> 8], 1);
        pairs[pos] = r | ((c & 255) << 17);
    }
}

// one block per bin, 1024 threads: inline bin-total scan -> degree count ->
// LDS scan -> rp/dinv -> place eidx
__global__ __launch_bounds__(1024) void k_binfinish(
    const int* __restrict__ gpos, const int* __restrict__ bsums,
    const int* __restrict__ pairs,
    int* __restrict__ rp, float* __restrict__ dinv, int* __restrict__ eidx) {
    __shared__ int cnt[256];
    __shared__ int tmp[256];
    __shared__ int sc[512];
    int b = blockIdx.x, t = threadIdx.x;
    int n0 = b << 8;
    int bv = 0;
    if (t < 512) { bv = (t < NBIN) ? bsums[t] : 0; sc[t] = bv; }
    __syncthreads();
    for (int off = 1; off < 512; off <<= 1) {
        int u = (t < 512 && t >= off) ? sc[t - off] : 0;
        __syncthreads();
        if (t < 512) sc[t] += u;
        __syncthreads();
    }
    if (t < 512) sc[t] -= bv;   // exclusive prefix of bin totals
    __syncthreads();
    int beg = gpos[b * SBLK] + sc[b];
    int end = (b + 1 < NBIN) ? gpos[(b + 1) * SBLK] + sc[b + 1] : N_EDGES;

    if (t < 256) cnt[t] = 0;
    __syncthreads();
    for (int i = beg + t; i < end; i += 1024)
        atomicAdd(&cnt[(pairs[i] >> 17) & 255], 1);
    __syncthreads();
    int v = 0;
    if (t < 256) { v = cnt[t]; tmp[t] = v; }
    __syncthreads();
    for (int off = 1; off < 256; off <<= 1) {
        int u = (t < 256 && t >= off) ? tmp[t - off] : 0;
        __syncthreads();
        if (t < 256) tmp[t] += u;
        __syncthreads();
    }
    if (t < 256) {
        int rpv = beg + tmp[t] - v;
        int n = n0 + t;
        if (n < N_NODES) {
            rp[n] = rpv;
            dinv[n] = rsqrtf(1.0f + (float)v);
        }
        cnt[t] = rpv;   // placement cursor
    }
    if (b == NBIN - 1 && t == 0) rp[N_NODES] = N_EDGES;
    __syncthreads();
    for (int i = beg + t; i < end; i += 1024) {
        int p = pairs[i];
        int pos = atomicAdd(&cnt[(p >> 17) & 255], 1);
        eidx[pos] = p & 0x1FFFF;
    }
}

// -------- layer 0 GEMM (MFMA): yh = fp16( dinv[row] * (x @ W0) )
// Rows N_NODES..100031 (grid padding) are written as ZEROS.
__global__ __launch_bounds__(256) void k_gemm1(
    const float* __restrict__ x, const __half* __restrict__ wt0,
    const float* __restrict__ dinv, __half* __restrict__ yh) {
    int w = threadIdx.x >> 6, l = threadIdx.x & 63;
    int g = l >> 4, c16 = l & 15;
    int row = blockIdx.x * 64 + w * 16 + c16;
    int rl = (row < N_NODES) ? row : (N_NODES - 1);
    const float* xr = x + (size_t)rl * N_FEAT;

    f16x8 a[4];
    #pragma unroll
    for (int s = 0; s < 4; ++s) {
        int k0 = 32 * s + 8 * g;
        float4 f0 = (k0 + 3 < N_FEAT) ? *(const float4*)(xr + k0)
                                      : make_float4(0.f, 0.f, 0.f, 0.f);
        float4 f1 = (k0 + 7 < N_FEAT) ? *(const float4*)(xr + k0 + 4)
                                      : make_float4(0.f, 0.f, 0.f, 0.f);
        a[s][0] = (_Float16)f0.x; a[s][1] = (_Float16)f0.y;
        a[s][2] = (_Float16)f0.z; a[s][3] = (_Float16)f0.w;
        a[s][4] = (_Float16)f1.x; a[s][5] = (_Float16)f1.y;
        a[s][6] = (_Float16)f1.z; a[s][7] = (_Float16)f1.w;
    }
    f32x4 acc0 = {0,0,0,0}, acc1 = {0,0,0,0}, acc2 = {0,0,0,0}, acc3 = {0,0,0,0};
    #pragma unroll
    for (int s = 0; s < 4; ++s) {
        int ko = 32 * s + 8 * g;
        f16x8 b0 = *(const f16x8*)(wt0 + (0 * 16 + c16) * 128 + ko);
        f16x8 b1 = *(const f16x8*)(wt0 + (1 * 16 + c16) * 128 + ko);
        f16x8 b2 = *(const f16x8*)(wt0 + (2 * 16 + c16) * 128 + ko);
        f16x8 b3 = *(const f16x8*)(wt0 + (3 * 16 + c16) * 128 + ko);
        acc0 = __builtin_amdgcn_mfma_f32_16x16x32_f16(a[s], b0, acc0, 0, 0, 0);
        acc1 = __builtin_amdgcn_mfma_f32_16x16x32_f16(a[s], b1, acc1, 0, 0, 0);
        acc2 = __builtin_amdgcn_mfma_f32_16x16x32_f16(a[s], b2, acc2, 0, 0, 0);
        acc3 = __builtin_amdgcn_mfma_f32_16x16x32_f16(a[s], b3, acc3, 0, 0, 0);
    }
    int orow = blockIdx.x * 64 + w * 16 + 4 * g;
    #pragma unroll
    for (int r = 0; r < 4; ++r) {
        int rr = orow + r;                      // grid max = 100031
        float di = (rr < N_NODES) ? dinv[rr] : 0.0f;
        size_t base = (size_t)rr * HIDDEN + c16;
        yh[base +  0] = __float2half(di * acc0[r]);
        yh[base + 16] = __float2half(di * acc1[r]);
        yh[base + 32] = __float2half(di * acc2[r]);
        yh[base + 48] = __float2half(di * acc3[r]);
    }
}

// -------- fused layer-0 aggregate + layer-1 GEMM --------------------------
// fp16 pairwise-tree reduce (R15); zh rows padded to 128 B (one line/gather).
__global__ __launch_bounds__(256) void k_agg0(
    const int* __restrict__ rp, const int* __restrict__ eidx,
    const float* __restrict__ dinv, const __half* __restrict__ yh,
    const float* __restrict__ b0, const __half* __restrict__ wt1,
    __half* __restrict__ zh) {
    __shared__ __half hs[16][64];   // rows 0-7 = this block's hr; 8-15 zero
    int t = blockIdx.x * 256 + threadIdx.x;
    int n = t >> 5;                 // grid exactly 12500 blocks: n < N_NODES
    int hl = threadIdx.x & 31;
    int nl = threadIdx.x >> 5;

    ((__half2*)hs)[256 + threadIdx.x] = __floats2half2_rn(0.f, 0.f); // rows 8-15

    int beg = rp[n], end = rp[n + 1];
    int deg = end - beg;
    int se = (beg + hl < end) ? eidx[beg + hl] : 0;
    const __half2* yh2 = (const __half2*)yh;
    float2 fs = __half22float2(yh2[(size_t)n * 32 + hl]);   // self loop
    float ax = fs.x, ay = fs.y;
    int m = deg < 32 ? deg : 32;
    int base = threadIdx.x & 32;
    const __half2 hz = __floats2half2_rn(0.f, 0.f);

    {   // batch 0: slots 0..15
        __half2 h[16];
        #pragma unroll
        for (int k = 0; k < 16; ++k) {
            int s = __shfl(se, base + k);
            h[k] = yh2[(size_t)s * 32 + hl];
        }
        #pragma unroll
        for (int k = 0; k < 16; ++k) h[k] = (m > k) ? h[k] : hz;
        #pragma unroll
        for (int s2 = 8; s2 >= 1; s2 >>= 1) {
            #pragma unroll
            for (int k = 0; k < s2; ++k) h[k] = __hadd2(h[2 * k], h[2 * k + 1]);
        }
        float2 bs = __half22float2(h[0]);
        ax += bs.x; ay += bs.y;
    }
    if (m > 16) {   // batch 1: slots 16..31
        __half2 h[16];
        #pragma unroll
        for (int k = 0; k < 16; ++k) {
            int s = __shfl(se, base + 16 + k);
            h[k] = yh2[(size_t)s * 32 + hl];
        }
        #pragma unroll
        for (int k = 0; k < 16; ++k) h[k] = (m > 16 + k) ? h[k] : hz;
        #pragma unroll
        for (int s2 = 8; s2 >= 1; s2 >>= 1) {
            #pragma unroll
            for (int k = 0; k < s2; ++k) h[k] = __hadd2(h[2 * k], h[2 * k + 1]);
        }
        float2 bs = __half22float2(h[0]);
        ax += bs.x; ay += bs.y;
    }
    if (deg > 32) {
        for (int e = beg + 32; e < end; ++e) {
            int s = eidx[e];
            float2 fv = __half22float2(yh2[(size_t)s * 32 + hl]);
            ax += fv.x; ay += fv.y;
        }
    }
    float di = dinv[n];
    float2 b2 = ((const float2*)b0)[hl];
    float o0 = fmaxf(di * ax + b2.x, 0.0f);
    float o1 = fmaxf(di * ay + b2.y, 0.0f);
    ((__half2*)hs)[nl * 32 + hl] = __floats2half2_rn(o0, o1);
    __syncthreads();

    // ---- epilogue: wave 0 computes zh rows for the block's 8 nodes -------
    if (threadIdx.x < 64) {
        int l = threadIdx.x;
        int g = l >> 4, c16 = l & 15;
        f16x8 a0 = *(const f16x8*)(&hs[c16][8 * g]);
        f16x8 a1 = *(const f16x8*)(&hs[c16][32 + 8 * g]);
        f32x4 acc0 = {0,0,0,0}, acc1 = {0,0,0,0}, acc2 = {0,0,0,0};
        #pragma unroll
        for (int s = 0; s < 2; ++s) {
            int ko = 32 * s + 8 * g;
            f16x8 b0f = *(const f16x8*)(wt1 + (0 * 16 + c16) * 64 + ko);
            f16x8 b1f = *(const f16x8*)(wt1 + (1 * 16 + c16) * 64 + ko);
            f16x8 b2f = *(const f16x8*)(wt1 + (2 * 16 + c16) * 64 + ko);
            f16x8 av = s ? a1 : a0;
            acc0 = __builtin_amdgcn_mfma_f32_16x16x32_f16(av, b0f, acc0, 0, 0, 0);
            acc1 = __builtin_amdgcn_mfma_f32_16x16x32_f16(av, b1f, acc1, 0, 0, 0);
            acc2 = __builtin_amdgcn_mfma_f32_16x16x32_f16(av, b2f, acc2, 0, 0, 0);
        }
        if (g < 2) {   // D rows 0..7 are the valid ones
            int nrow = blockIdx.x * 8 + 4 * g;
            #pragma unroll
            for (int r = 0; r < 4; ++r) {
                float dr = dinv[nrow + r];
                size_t bz = (size_t)(nrow + r) * ZROWH + c16;   // 128 B rows
                zh[bz +  0] = __float2half(dr * acc0[r]);
                zh[bz + 16] = __float2half(dr * acc1[r]);
                zh[bz + 32] = __float2half(dr * acc2[r]);
            }
        }
    }
}

// -------- layer 1 aggregate: out[n] = dinv[n]*(zh[n]+sum zh[src]) + b1 ------
// zh rows are 128 B aligned: every gather is exactly one cache line.
__global__ __launch_bounds__(256) void k_agg1(
    const int* __restrict__ rp, const int* __restrict__ eidx,
    const float* __restrict__ dinv, const __half* __restrict__ zh,
    const float* __restrict__ b1, float* __restrict__ out) {
    int t = blockIdx.x * 256 + threadIdx.x;
    int n = t >> 5;
    int hl = threadIdx.x & 31;
    if (n >= N_NODES) return;
    int beg = rp[n], end = rp[n + 1];
    int deg = end - beg;
    int se = (beg + hl < end) ? eidx[beg + hl] : 0;
    const __half2* zh2 = (const __half2*)zh;
    float ax = 0.0f, ay = 0.0f;
    if (hl < 24) {
        float2 f = __half22float2(zh2[(size_t)n * 32 + hl]);
        ax = f.x; ay = f.y;
    }
    int m = deg < 32 ? deg : 32;
    int base = threadIdx.x & 32;
    const __half2 hz = __floats2half2_rn(0.f, 0.f);

    {   // batch 0: slots 0..15
        int sidx[16];
        #pragma unroll
        for (int k = 0; k < 16; ++k) sidx[k] = __shfl(se, base + k);
        if (hl < 24) {
            __half2 h[16];
            #pragma unroll
            for (int k = 0; k < 16; ++k) h[k] = zh2[(size_t)sidx[k] * 32 + hl];
            #pragma unroll
            for (int k = 0; k < 16; ++k) h[k] = (m > k) ? h[k] : hz;
            #pragma unroll
            for (int s2 = 8; s2 >= 1; s2 >>= 1) {
                #pragma unroll
                for (int k = 0; k < s2; ++k) h[k] = __hadd2(h[2 * k], h[2 * k + 1]);
            }
            float2 bs = __half22float2(h[0]);
            ax += bs.x; ay += bs.y;
        }
    }
    if (m > 16) {   // batch 1: slots 16..31
        int sidx[16];
        #pragma unroll
        for (int k = 0; k < 16; ++k) sidx[k] = __shfl(se, base + 16 + k);
        if (hl < 24) {
            __half2 h[16];
            #pragma unroll
            for (int k = 0; k < 16; ++k) h[k] = zh2[(size_t)sidx[k] * 32 + hl];
            #pragma unroll
            for (int k = 0; k < 16; ++k) h[k] = (m > 16 + k) ? h[k] : hz;
            #pragma unroll
            for (int s2 = 8; s2 >= 1; s2 >>= 1) {
                #pragma unroll
                for (int k = 0; k < s2; ++k) h[k] = __hadd2(h[2 * k], h[2 * k + 1]);
            }
            float2 bs = __half22float2(h[0]);
            ax += bs.x; ay += bs.y;
        }
    }
    if (deg > 32) {
        for (int e = beg + 32; e < end; ++e) {
            int s = eidx[e];
            if (hl < 24) {
                float2 fv = __half22float2(zh2[(size_t)s * 32 + hl]);
                ax += fv.x; ay += fv.y;
            }
        }
    }
    if (hl < 24) {
        float di = dinv[n];
        out[(size_t)n * N_CLASSES + 2 * hl] = di * ax + b1[2 * hl];
        if (hl < 23)
            out[(size_t)n * N_CLASSES + 2 * hl + 1] = di * ay + b1[2 * hl + 1];
    }
}

extern "C" void kernel_launch(void* const* d_in, const int* in_sizes, int n_in,
                              void* d_out, int out_size, void* d_ws, size_t ws_size,
                              hipStream_t stream) {
    const float* x  = (const float*)d_in[0];
    const int*   ei = (const int*)d_in[1];
    const float* W0 = (const float*)d_in[2];
    const float* b0 = (const float*)d_in[3];
    const float* W1 = (const float*)d_in[4];
    const float* b1 = (const float*)d_in[5];
    float* out = (float*)d_out;

    char* ws = (char*)d_ws;
    float*  dinv  = (float*)(ws);                         // 400 KB
    int*    rp    = (int*)(ws + 412 * 1024);              // 400 KB + 4
    int*    bsums = (int*)(ws + 824 * 1024);              // 1.6 KB (391 ints)
    int*    gh    = (int*)(ws + 828 * 1024);              // 782 KB
    int*    gpos  = (int*)(ws + 1612 * 1024);             // 782 KB
    __half* wt0   = (__half*)(ws + 2400 * 1024);          // 16 KB
    __half* wt1   = (__half*)(ws + 2420 * 1024);          // 6 KB
    int*    eidx  = (int*)(ws + 2428 * 1024);             // 6.4 MB -> ~8.8 MB
    __half* yh    = (__half*)(ws + 10ull * 1024 * 1024);  // 100032 rows = 12.81 MB
    __half* zh    = (__half*)(ws + 23ull * 1024 * 1024);  // 100000*128 B = 12.8 MB
    int*    pairs = (int*)zh;   // 6.4 MB alias: dead before k_agg0 writes zh

    const int* erow = ei;             // edge_index[0] (sources)
    const int* ecol = ei + N_EDGES;   // edge_index[1] (destinations)

    // radix pass (wprep fused into hist; bin-total scan inlined in consumers)
    k_hist  <<<SBLK, 256, 0, stream>>>(ecol, gh, W0, W1, wt0, wt1);
    k_gscan1<<<NBIN, 512, 0, stream>>>(gh, gpos, bsums, NHIST);
    k_radix_scatter<<<SBLK, 512, 0, stream>>>(erow, ecol, gpos, bsums, pairs);
    k_binfinish<<<NBIN, 1024, 0, stream>>>(gpos, bsums, pairs, rp, dinv, eidx);

    // layer 0 GEMM, then fused (layer-0 aggregate + layer-1 GEMM)
    k_gemm1<<<(N_NODES + 63) / 64, 256, 0, stream>>>(x, wt0, dinv, yh);
    k_agg0 <<<(N_NODES * 32) / 256, 256, 0, stream>>>(rp, eidx, dinv, yh, b0, wt1, zh);

    // layer 1 aggregate
    k_agg1 <<<(N_NODES * 32) / 256, 256, 0, stream>>>(rp, eidx, dinv, zh, b1, out);
}

// Round 18
// 127.474 us; speedup vs baseline: 1.0319x; 1.0006x over previous
//
#include <hip/hip_runtime.h>
#include <hip/hip_fp16.h>

#define N_NODES   100000
#define N_EDGES   1600000
#define N_FEAT    100
#define HIDDEN    64
#define N_CLASSES 47
#define ZROWH     64                         // zh row stride in halves (128 B line)
#define NBIN      ((N_NODES + 255) / 256)   // 391 radix bins (dest >> 8)
#define SBLK      512                        // scatter blocks
#define CHUNK     (N_EDGES / SBLK)           // 3125 edges per scatter block
#define NHIST     (NBIN * SBLK)              // 200192 histogram entries
#define WT0_ELEMS (HIDDEN * 128)             // 8192
#define WT1_ELEMS (48 * 64)                  // 3072
#define WPREP_N   (WT0_ELEMS + WT1_ELEMS)    // 11264

typedef _Float16 f16x8 __attribute__((ext_vector_type(8)));
typedef float f32x4 __attribute__((ext_vector_type(4)));

// ---------------- scan: 512-thread blocks, one block per bin ----------------

__global__ __launch_bounds__(512) void k_gscan1(const int* __restrict__ in,
                                                int* __restrict__ out,
                                                int* __restrict__ sums, int n) {
    __shared__ int tmp[512];
    int i = blockIdx.x * 512 + threadIdx.x;
    int v = (i < n) ? in[i] : 0;
    tmp[threadIdx.x] = v;
    __syncthreads();
    for (int off = 1; off < 512; off <<= 1) {
        int t = (threadIdx.x >= off) ? tmp[threadIdx.x - off] : 0;
        __syncthreads();
        tmp[threadIdx.x] += t;
        __syncthreads();
    }
    if (i < n) out[i] = tmp[threadIdx.x] - v;   // bin-local exclusive
    if (threadIdx.x == 511) sums[blockIdx.x] = tmp[511];   // bin total
}

// ---------------- radix pass: bin = dest >> 8 (256 nodes/bin) ----------------

// fused: blocks 0..43 also do the weight transpose (wprep)
__global__ __launch_bounds__(256) void k_hist(const int* __restrict__ ecol,
                                              int* __restrict__ gh,
                                              const float* __restrict__ W0,
                                              const float* __restrict__ W1,
                                              __half* __restrict__ wt0,
                                              __half* __restrict__ wt1) {
    int wi = blockIdx.x * 256 + threadIdx.x;
    if (wi < WT0_ELEMS) {
        int n = wi >> 7, k = wi & 127;
        wt0[wi] = __float2half((k < N_FEAT) ? W0[k * HIDDEN + n] : 0.0f);
    } else if (wi < WPREP_N) {
        int j = wi - WT0_ELEMS;
        int n = j >> 6, k = j & 63;
        wt1[j] = __float2half((n < N_CLASSES) ? W1[k * N_CLASSES + n] : 0.0f);
    }

    __shared__ int lh[NBIN];
    int b = blockIdx.x, t = threadIdx.x;
    for (int i = t; i < NBIN; i += 256) lh[i] = 0;
    __syncthreads();
    int e0 = b * CHUNK;
    for (int i = t; i < CHUNK; i += 256)
        atomicAdd(&lh[ecol[e0 + i] >> 8], 1);
    __syncthreads();
    for (int i = t; i < NBIN; i += 256) gh[i * SBLK + b] = lh[i];
}

// 512 threads; inline exclusive scan of the 391 bin totals (replaces gscan2).
// payload: row (17 bits) | (dest & 255) << 17
__global__ __launch_bounds__(512) void k_radix_scatter(
    const int* __restrict__ erow, const int* __restrict__ ecol,
    const int* __restrict__ gpos, const int* __restrict__ bsums,
    int* __restrict__ pairs) {
    __shared__ int lc[NBIN];
    __shared__ int sc[512];
    int b = blockIdx.x, t = threadIdx.x;
    int bv = (t < NBIN) ? bsums[t] : 0;
    sc[t] = bv;
    __syncthreads();
    for (int off = 1; off < 512; off <<= 1) {
        int u = (t >= off) ? sc[t - off] : 0;
        __syncthreads();
        sc[t] += u;
        __syncthreads();
    }
    if (t < NBIN) lc[t] = gpos[t * SBLK + b] + sc[t] - bv;   // + excl prefix
    __syncthreads();
    int e0 = b * CHUNK;
    for (int i = t; i < CHUNK; i += 512) {
        int e = e0 + i;
        int r = erow[e], c = ecol[e];
        int pos = atomicAdd(&lc[c >> 8], 1);
        pairs[pos] = r | ((c & 255) << 17);
    }
}

// one block per bin, 1024 threads: inline bin-total scan -> degree count ->
// LDS scan -> rp/dinv -> place eidx
__global__ __launch_bounds__(1024) void k_binfinish(
    const int* __restrict__ gpos, const int* __restrict__ bsums,
    const int* __restrict__ pairs,
    int* __restrict__ rp, float* __restrict__ dinv, int* __restrict__ eidx) {
    __shared__ int cnt[256];
    __shared__ int tmp[256];
    __shared__ int sc[512];
    int b = blockIdx.x, t = threadIdx.x;
    int n0 = b << 8;
    int bv = 0;
    if (t < 512) { bv = (t < NBIN) ? bsums[t] : 0; sc[t] = bv; }
    __syncthreads();
    for (int off = 1; off < 512; off <<= 1) {
        int u = (t < 512 && t >= off) ? sc[t - off] : 0;
        __syncthreads();
        if (t < 512) sc[t] += u;
        __syncthreads();
    }
    if (t < 512) sc[t] -= bv;   // exclusive prefix of bin totals
    __syncthreads();
    int beg = gpos[b * SBLK] + sc[b];
    int end = (b + 1 < NBIN) ? gpos[(b + 1) * SBLK] + sc[b + 1] : N_EDGES;

    if (t < 256) cnt[t] = 0;
    __syncthreads();
    for (int i = beg + t; i < end; i += 1024)
        atomicAdd(&cnt[(pairs[i] >> 17) & 255], 1);
    __syncthreads();
    int v = 0;
    if (t < 256) { v = cnt[t]; tmp[t] = v; }
    __syncthreads();
    for (int off = 1; off < 256; off <<= 1) {
        int u = (t < 256 && t >= off) ? tmp[t - off] : 0;
        __syncthreads();
        if (t < 256) tmp[t] += u;
        __syncthreads();
    }
    if (t < 256) {
        int rpv = beg + tmp[t] - v;
        int n = n0 + t;
        if (n < N_NODES) {
            rp[n] = rpv;
            dinv[n] = rsqrtf(1.0f + (float)v);
        }
        cnt[t] = rpv;   // placement cursor
    }
    if (b == NBIN - 1 && t == 0) rp[N_NODES] = N_EDGES;
    __syncthreads();
    for (int i = beg + t; i < end; i += 1024) {
        int p = pairs[i];
        int pos = atomicAdd(&cnt[(p >> 17) & 255], 1);
        eidx[pos] = p & 0x1FFFF;
    }
}

// -------- layer 0 GEMM (MFMA): yh = fp16( dinv[row] * (x @ W0) )
// Rows N_NODES..100031 (grid padding) are written as ZEROS.
__global__ __launch_bounds__(256) void k_gemm1(
    const float* __restrict__ x, const __half* __restrict__ wt0,
    const float* __restrict__ dinv, __half* __restrict__ yh) {
    int w = threadIdx.x >> 6, l = threadIdx.x & 63;
    int g = l >> 4, c16 = l & 15;
    int row = blockIdx.x * 64 + w * 16 + c16;
    int rl = (row < N_NODES) ? row : (N_NODES - 1);
    const float* xr = x + (size_t)rl * N_FEAT;

    f16x8 a[4];
    #pragma unroll
    for (int s = 0; s < 4; ++s) {
        int k0 = 32 * s + 8 * g;
        float4 f0 = (k0 + 3 < N_FEAT) ? *(const float4*)(xr + k0)
                                      : make_float4(0.f, 0.f, 0.f, 0.f);
        float4 f1 = (k0 + 7 < N_FEAT) ? *(const float4*)(xr + k0 + 4)
                                      : make_float4(0.f, 0.f, 0.f, 0.f);
        a[s][0] = (_Float16)f0.x; a[s][1] = (_Float16)f0.y;
        a[s][2] = (_Float16)f0.z; a[s][3] = (_Float16)f0.w;
        a[s][4] = (_Float16)f1.x; a[s][5] = (_Float16)f1.y;
        a[s][6] = (_Float16)f1.z; a[s][7] = (_Float16)f1.w;
    }
    f32x4 acc0 = {0,0,0,0}, acc1 = {0,0,0,0}, acc2 = {0,0,0,0}, acc3 = {0,0,0,0};
    #pragma unroll
    for (int s = 0; s < 4; ++s) {
        int ko = 32 * s + 8 * g;
        f16x8 b0 = *(const f16x8*)(wt0 + (0 * 16 + c16) * 128 + ko);
        f16x8 b1 = *(const f16x8*)(wt0 + (1 * 16 + c16) * 128 + ko);
        f16x8 b2 = *(const f16x8*)(wt0 + (2 * 16 + c16) * 128 + ko);
        f16x8 b3 = *(const f16x8*)(wt0 + (3 * 16 + c16) * 128 + ko);
        acc0 = __builtin_amdgcn_mfma_f32_16x16x32_f16(a[s], b0, acc0, 0, 0, 0);
        acc1 = __builtin_amdgcn_mfma_f32_16x16x32_f16(a[s], b1, acc1, 0, 0, 0);
        acc2 = __builtin_amdgcn_mfma_f32_16x16x32_f16(a[s], b2, acc2, 0, 0, 0);
        acc3 = __builtin_amdgcn_mfma_f32_16x16x32_f16(a[s], b3, acc3, 0, 0, 0);
    }
    int orow = blockIdx.x * 64 + w * 16 + 4 * g;
    #pragma unroll
    for (int r = 0; r < 4; ++r) {
        int rr = orow + r;                      // grid max = 100031
        float di = (rr < N_NODES) ? dinv[rr] : 0.0f;
        size_t base = (size_t)rr * HIDDEN + c16;
        yh[base +  0] = __float2half(di * acc0[r]);
        yh[base + 16] = __float2half(di * acc1[r]);
        yh[base + 32] = __float2half(di * acc2[r]);
        yh[base + 48] = __float2half(di * acc3[r]);
    }
}

// -------- fused layer-0 aggregate + layer-1 GEMM --------------------------
// fp16 pairwise-tree reduce (R15); zh rows padded to 128 B (one line/gather).
__global__ __launch_bounds__(256) void k_agg0(
    const int* __restrict__ rp, const int* __restrict__ eidx,
    const float* __restrict__ dinv, const __half* __restrict__ yh,
    const float* __restrict__ b0, const __half* __restrict__ wt1,
    __half* __restrict__ zh) {
    __shared__ __half hs[16][64];   // rows 0-7 = this block's hr; 8-15 zero
    int t = blockIdx.x * 256 + threadIdx.x;
    int n = t >> 5;                 // grid exactly 12500 blocks: n < N_NODES
    int hl = threadIdx.x & 31;
    int nl = threadIdx.x >> 5;

    ((__half2*)hs)[256 + threadIdx.x] = __floats2half2_rn(0.f, 0.f); // rows 8-15

    int beg = rp[n], end = rp[n + 1];
    int deg = end - beg;
    int se = (beg + hl < end) ? eidx[beg + hl] : 0;
    const __half2* yh2 = (const __half2*)yh;
    float2 fs = __half22float2(yh2[(size_t)n * 32 + hl]);   // self loop
    float ax = fs.x, ay = fs.y;
    int m = deg < 32 ? deg : 32;
    int base = threadIdx.x & 32;
    const __half2 hz = __floats2half2_rn(0.f, 0.f);

    {   // batch 0: slots 0..15
        __half2 h[16];
        #pragma unroll
        for (int k = 0; k < 16; ++k) {
            int s = __shfl(se, base + k);
            h[k] = yh2[(size_t)s * 32 + hl];
        }
        #pragma unroll
        for (int k = 0; k < 16; ++k) h[k] = (m > k) ? h[k] : hz;
        #pragma unroll
        for (int s2 = 8; s2 >= 1; s2 >>= 1) {
            #pragma unroll
            for (int k = 0; k < s2; ++k) h[k] = __hadd2(h[2 * k], h[2 * k + 1]);
        }
        float2 bs = __half22float2(h[0]);
        ax += bs.x; ay += bs.y;
    }
    if (m > 16) {   // batch 1: slots 16..31
        __half2 h[16];
        #pragma unroll
        for (int k = 0; k < 16; ++k) {
            int s = __shfl(se, base + 16 + k);
            h[k] = yh2[(size_t)s * 32 + hl];
        }
        #pragma unroll
        for (int k = 0; k < 16; ++k) h[k] = (m > 16 + k) ? h[k] : hz;
        #pragma unroll
        for (int s2 = 8; s2 >= 1; s2 >>= 1) {
            #pragma unroll
            for (int k = 0; k < s2; ++k) h[k] = __hadd2(h[2 * k], h[2 * k + 1]);
        }
        float2 bs = __half22float2(h[0]);
        ax += bs.x; ay += bs.y;
    }
    if (deg > 32) {
        for (int e = beg + 32; e < end; ++e) {
            int s = eidx[e];
            float2 fv = __half22float2(yh2[(size_t)s * 32 + hl]);
            ax += fv.x; ay += fv.y;
        }
    }
    float di = dinv[n];
    float2 b2 = ((const float2*)b0)[hl];
    float o0 = fmaxf(di * ax + b2.x, 0.0f);
    float o1 = fmaxf(di * ay + b2.y, 0.0f);
    ((__half2*)hs)[nl * 32 + hl] = __floats2half2_rn(o0, o1);
    __syncthreads();

    // ---- epilogue: wave 0 computes zh rows for the block's 8 nodes -------
    if (threadIdx.x < 64) {
        int l = threadIdx.x;
        int g = l >> 4, c16 = l & 15;
        f16x8 a0 = *(const f16x8*)(&hs[c16][8 * g]);
        f16x8 a1 = *(const f16x8*)(&hs[c16][32 + 8 * g]);
        f32x4 acc0 = {0,0,0,0}, acc1 = {0,0,0,0}, acc2 = {0,0,0,0};
        #pragma unroll
        for (int s = 0; s < 2; ++s) {
            int ko = 32 * s + 8 * g;
            f16x8 b0f = *(const f16x8*)(wt1 + (0 * 16 + c16) * 64 + ko);
            f16x8 b1f = *(const f16x8*)(wt1 + (1 * 16 + c16) * 64 + ko);
            f16x8 b2f = *(const f16x8*)(wt1 + (2 * 16 + c16) * 64 + ko);
            f16x8 av = s ? a1 : a0;
            acc0 = __builtin_amdgcn_mfma_f32_16x16x32_f16(av, b0f, acc0, 0, 0, 0);
            acc1 = __builtin_amdgcn_mfma_f32_16x16x32_f16(av, b1f, acc1, 0, 0, 0);
            acc2 = __builtin_amdgcn_mfma_f32_16x16x32_f16(av, b2f, acc2, 0, 0, 0);
        }
        if (g < 2) {   // D rows 0..7 are the valid ones
            int nrow = blockIdx.x * 8 + 4 * g;
            #pragma unroll
            for (int r = 0; r < 4; ++r) {
                float dr = dinv[nrow + r];
                size_t bz = (size_t)(nrow + r) * ZROWH + c16;   // 128 B rows
                zh[bz +  0] = __float2half(dr * acc0[r]);
                zh[bz + 16] = __float2half(dr * acc1[r]);
                zh[bz + 32] = __float2half(dr * acc2[r]);
            }
        }
    }
}

// -------- layer 1 aggregate: out[n] = dinv[n]*(zh[n]+sum zh[src]) + b1 ------
// zh rows are 128 B aligned: every gather is exactly one cache line.
__global__ __launch_bounds__(256) void k_agg1(
    const int* __restrict__ rp, const int* __restrict__ eidx,
    const float* __restrict__ dinv, const __half* __restrict__ zh,
    const float* __restrict__ b1, float* __restrict__ out) {
    int t = blockIdx.x * 256 + threadIdx.x;
    int n = t >> 5;
    int hl = threadIdx.x & 31;
    if (n >= N_NODES) return;
    int beg = rp[n], end = rp[n + 1];
    int deg = end - beg;
    int se = (beg + hl < end) ? eidx[beg + hl] : 0;
    const __half2* zh2 = (const __half2*)zh;
    float ax = 0.0f, ay = 0.0f;
    if (hl < 24) {
        float2 f = __half22float2(zh2[(size_t)n * 32 + hl]);
        ax = f.x; ay = f.y;
    }
    int m = deg < 32 ? deg : 32;
    int base = threadIdx.x & 32;
    const __half2 hz = __floats2half2_rn(0.f, 0.f);

    {   // batch 0: slots 0..15
        int sidx[16];
        #pragma unroll
        for (int k = 0; k < 16; ++k) sidx[k] = __shfl(se, base + k);
        if (hl < 24) {
            __half2 h[16];
            #pragma unroll
            for (int k = 0; k < 16; ++k) h[k] = zh2[(size_t)sidx[k] * 32 + hl];
            #pragma unroll
            for (int k = 0; k < 16; ++k) h[k] = (m > k) ? h[k] : hz;
            #pragma unroll
            for (int s2 = 8; s2 >= 1; s2 >>= 1) {
                #pragma unroll
                for (int k = 0; k < s2; ++k) h[k] = __hadd2(h[2 * k], h[2 * k + 1]);
            }
            float2 bs = __half22float2(h[0]);
            ax += bs.x; ay += bs.y;
        }
    }
    if (m > 16) {   // batch 1: slots 16..31
        int sidx[16];
        #pragma unroll
        for (int k = 0; k < 16; ++k) sidx[k] = __shfl(se, base + 16 + k);
        if (hl < 24) {
            __half2 h[16];
            #pragma unroll
            for (int k = 0; k < 16; ++k) h[k] = zh2[(size_t)sidx[k] * 32 + hl];
            #pragma unroll
            for (int k = 0; k < 16; ++k) h[k] = (m > 16 + k) ? h[k] : hz;
            #pragma unroll
            for (int s2 = 8; s2 >= 1; s2 >>= 1) {
                #pragma unroll
                for (int k = 0; k < s2; ++k) h[k] = __hadd2(h[2 * k], h[2 * k + 1]);
            }
            float2 bs = __half22float2(h[0]);
            ax += bs.x; ay += bs.y;
        }
    }
    if (deg > 32) {
        for (int e = beg + 32; e < end; ++e) {
            int s = eidx[e];
            if (hl < 24) {
                float2 fv = __half22float2(zh2[(size_t)s * 32 + hl]);
                ax += fv.x; ay += fv.y;
            }
        }
    }
    if (hl < 24) {
        float di = dinv[n];
        out[(size_t)n * N_CLASSES + 2 * hl] = di * ax + b1[2 * hl];
        if (hl < 23)
            out[(size_t)n * N_CLASSES + 2 * hl + 1] = di * ay + b1[2 * hl + 1];
    }
}

extern "C" void kernel_launch(void* const* d_in, const int* in_sizes, int n_in,
                              void* d_out, int out_size, void* d_ws, size_t ws_size,
                              hipStream_t stream) {
    const float* x  = (const float*)d_in[0];
    const int*   ei = (const int*)d_in[1];
    const float* W0 = (const float*)d_in[2];
    const float* b0 = (const float*)d_in[3];
    const float* W1 = (const float*)d_in[4];
    const float* b1 = (const float*)d_in[5];
    float* out = (float*)d_out;

    char* ws = (char*)d_ws;
    float*  dinv  = (float*)(ws);                         // 400 KB
    int*    rp    = (int*)(ws + 412 * 1024);              // 400 KB + 4
    int*    bsums = (int*)(ws + 824 * 1024);              // 1.6 KB (391 ints)
    int*    gh    = (int*)(ws + 828 * 1024);              // 782 KB
    int*    gpos  = (int*)(ws + 1612 * 1024);             // 782 KB
    __half* wt0   = (__half*)(ws + 2400 * 1024);          // 16 KB
    __half* wt1   = (__half*)(ws + 2420 * 1024);          // 6 KB
    int*    eidx  = (int*)(ws + 2428 * 1024);             // 6.4 MB -> ~8.8 MB
    __half* yh    = (__half*)(ws + 10ull * 1024 * 1024);  // 100032 rows = 12.81 MB
    __half* zh    = (__half*)(ws + 23ull * 1024 * 1024);  // 100000*128 B = 12.8 MB
    int*    pairs = (int*)zh;   // 6.4 MB alias: dead before k_agg0 writes zh

    const int* erow = ei;             // edge_index[0] (sources)
    const int* ecol = ei + N_EDGES;   // edge_index[1] (destinations)

    // radix pass (wprep fused into hist; bin-total scan inlined in consumers)
    k_hist  <<<SBLK, 256, 0, stream>>>(ecol, gh, W0, W1, wt0, wt1);
    k_gscan1<<<NBIN, 512, 0, stream>>>(gh, gpos, bsums, NHIST);
    k_radix_scatter<<<SBLK, 512, 0, stream>>>(erow, ecol, gpos, bsums, pairs);
    k_binfinish<<<NBIN, 1024, 0, stream>>>(gpos, bsums, pairs, rp, dinv, eidx);

    // layer 0 GEMM, then fused (layer-0 aggregate + layer-1 GEMM)
    k_gemm1<<<(N_NODES + 63) / 64, 256, 0, stream>>>(x, wt0, dinv, yh);
    k_agg0 <<<(N_NODES * 32) / 256, 256, 0, stream>>>(rp, eidx, dinv, yh, b0, wt1, zh);

    // layer 1 aggregate
    k_agg1 <<<(N_NODES * 32) / 256, 256, 0, stream>>>(rp, eidx, dinv, zh, b1, out);
}